// Round 1
// 380.306 us; speedup vs baseline: 1.0247x; 1.0247x over previous
//
#include <hip/hip_runtime.h>

#define HH 256
#define WW 256
#define CC 96
#define BB 8

__device__ __forceinline__ float silu_of(float z) {
    return z / (1.0f + __expf(-z));
}

__global__ __launch_bounds__(256, 4)
void trifreq_kernel(const float* __restrict__ x,
                    const float* __restrict__ w_lo,
                    const float* __restrict__ w_mf,
                    const float* __restrict__ w_hf,
                    const float* __restrict__ gamma,
                    const float* __restrict__ beta,
                    const float* __restrict__ mean,
                    const float* __restrict__ var,
                    float* __restrict__ out)
{
    // xs: input tile with halo 4: tile-rel coords -4..67 -> idx = coord+4, stride 72.
    // +2 rows and +16 floats tail: the mf band stage vector-loads over-read up to
    // row 73 / element col 75; that garbage flows ONLY into tmp ring coords 65/66
    // which are never consumed (see tmp layout below).
    __shared__ __align__(16) float xs[74 * 72 + 16];
    // tmp: band/high-pass tile, coords -1..66 -> idx = coord+1, stride 68.
    // Conv needs coords -1..64 only; 65/66 are a garbage ring (written, and only
    // ever loaded into unused padding lanes of float4 reads).
    __shared__ __align__(16) float tmp[68 * 68];

    const int tid = threadIdx.x;
    const int tileIdx = blockIdx.x;          // 0..15
    const int c = blockIdx.y;                // 0..95 (concat order == input channel)
    const int b = blockIdx.z;                // 0..7
    const int th = (tileIdx >> 2) * 64;      // tile origin h
    const int tw = (tileIdx & 3) * 64;       // tile origin w

    const int g = c >> 5;                    // 0=lo,1=mf,2=hf
    const int ci = c & 31;
    const int c_out = ci * 3 + g;            // channel-shuffle output index

    const float* __restrict__ xin = x + (((size_t)b * CC + c) * (size_t)HH) * (size_t)WW;

    // ---------------- stage input tile + halo(4), zero outside image ----------------
    // 72 rows x 18 float4 (all segments 16B aligned; image bounds fall on float4 edges)
    for (int idx = tid; idx < 72 * 18; idx += 256) {
        const int r  = idx / 18;
        const int c4 = idx % 18;
        const int gh = th - 4 + r;
        const int gw = tw - 4 + 4 * c4;
        float4 v = make_float4(0.f, 0.f, 0.f, 0.f);
        if (gh >= 0 && gh < HH && gw >= 0 && gw + 3 < WW) {
            v = *reinterpret_cast<const float4*>(xin + (size_t)gh * WW + gw);
        }
        *reinterpret_cast<float4*>(&xs[r * 72 + 4 * c4]) = v;
    }
    __syncthreads();

    const int qr = (tid >> 4) << 2;   // output patch base row (0..60)
    const int qc = (tid & 15) << 2;   // output patch base col (0..60)
    float acc[4][4];

    if (g == 0) {
        // ---------------- low band: direct 5x5 depthwise conv ----------------
        const float* __restrict__ wp = w_lo + ci * 25;
        float wk[25];
        #pragma unroll
        for (int t = 0; t < 25; ++t) wk[t] = wp[t];
        #pragma unroll
        for (int i = 0; i < 4; ++i)
            #pragma unroll
            for (int j = 0; j < 4; ++j) acc[i][j] = 0.f;

        #pragma unroll
        for (int rr = 0; rr < 8; ++rr) {
            // x row tile-rel = qr-2+rr -> xs row idx qr+rr+2.
            // Needed elements: cols idx qc+2 .. qc+9 -> three aligned b128 at qc, qc+4, qc+8.
            const float* row = &xs[(qr + rr + 2) * 72 + qc];
            float v[12];
            *reinterpret_cast<float4*>(&v[0]) = *reinterpret_cast<const float4*>(row);
            *reinterpret_cast<float4*>(&v[4]) = *reinterpret_cast<const float4*>(row + 4);
            *reinterpret_cast<float4*>(&v[8]) = *reinterpret_cast<const float4*>(row + 8);
            #pragma unroll
            for (int i = 0; i < 4; ++i) {
                const int ki = rr - i;
                if (ki >= 0 && ki < 5) {
                    #pragma unroll
                    for (int j = 0; j < 4; ++j)
                        acc[i][j] += v[j + 2] * wk[ki * 5 + 0]
                                   + v[j + 3] * wk[ki * 5 + 1]
                                   + v[j + 4] * wk[ki * 5 + 2]
                                   + v[j + 5] * wk[ki * 5 + 3]
                                   + v[j + 6] * wk[ki * 5 + 4];
                }
            }
        }
    } else {
        if (g == 1) {
            // ---------------- mid band: bandpass = avg3 - avg7 into tmp ----------------
            for (int p = tid; p < 17 * 17; p += 256) {
                const int pr = p / 17, pc = p % 17;
                const int br = pr * 4 - 1, bc = pc * 4 - 1;   // tmp coord base (ring off = 1)
                float v7a[4][4] = {};
                float v3a[4][4] = {};
                #pragma unroll
                for (int rr = 0; rr < 10; ++rr) {
                    // window rows: xs idx pr*4 .. pr*4+9 (rows 72/73 = garbage pad -> ring only)
                    // window cols: xs idx pc*4 .. pc*4+9 -> three aligned b128 (over-read to +11)
                    const float* row = &xs[(pr * 4 + rr) * 72 + pc * 4];
                    float v[12];
                    *reinterpret_cast<float4*>(&v[0]) = *reinterpret_cast<const float4*>(row);
                    *reinterpret_cast<float4*>(&v[4]) = *reinterpret_cast<const float4*>(row + 4);
                    *reinterpret_cast<float4*>(&v[8]) = *reinterpret_cast<const float4*>(row + 8);
                    float h7[4], h3[4];
                    float s = v[0] + v[1] + v[2] + v[3] + v[4] + v[5] + v[6];
                    h7[0] = s;
                    h7[1] = h7[0] + v[7] - v[0];
                    h7[2] = h7[1] + v[8] - v[1];
                    h7[3] = h7[2] + v[9] - v[2];
                    #pragma unroll
                    for (int j = 0; j < 4; ++j) h3[j] = v[j + 2] + v[j + 3] + v[j + 4];
                    #pragma unroll
                    for (int k = 0; k < 4; ++k) {
                        if (rr >= k && rr <= k + 6) {         // pool7 rows: rr = k..k+6
                            #pragma unroll
                            for (int j = 0; j < 4; ++j) v7a[k][j] += h7[j];
                        }
                        if (rr >= k + 2 && rr <= k + 4) {     // pool3 rows: rr = k+2..k+4
                            #pragma unroll
                            for (int j = 0; j < 4; ++j) v3a[k][j] += h3[j];
                        }
                    }
                }
                // count_include_pad=False reciprocal counts (per row/col, hoisted)
                float r3h[4], r7h[4], r3w[4], r7w[4];
                #pragma unroll
                for (int i = 0; i < 4; ++i) {
                    const int hh = th + br + i;
                    const int a3 = min(hh + 1, HH - 1) - max(hh - 1, 0) + 1;
                    const int a7 = min(hh + 3, HH - 1) - max(hh - 3, 0) + 1;
                    r3h[i] = 1.0f / (float)a3;
                    r7h[i] = 1.0f / (float)a7;
                }
                #pragma unroll
                for (int j = 0; j < 4; ++j) {
                    const int ww = tw + bc + j;
                    const int a3 = min(ww + 1, WW - 1) - max(ww - 1, 0) + 1;
                    const int a7 = min(ww + 3, WW - 1) - max(ww - 3, 0) + 1;
                    r3w[j] = 1.0f / (float)a3;
                    r7w[j] = 1.0f / (float)a7;
                }
                #pragma unroll
                for (int i = 0; i < 4; ++i) {
                    const int hh = th + br + i;
                    float bpv[4];
                    #pragma unroll
                    for (int j = 0; j < 4; ++j) {
                        const int ww = tw + bc + j;
                        float bp = 0.f;
                        if (hh >= 0 && hh < HH && ww >= 0 && ww < WW)
                            bp = v3a[i][j] * (r3h[i] * r3w[j]) - v7a[i][j] * (r7h[i] * r7w[j]);
                        bpv[j] = bp;
                    }
                    // tmp idx row = pr*4+i, col = pc*4 .. +3 -> aligned b128 write
                    *reinterpret_cast<float4*>(&tmp[(pr * 4 + i) * 68 + pc * 4]) =
                        make_float4(bpv[0], bpv[1], bpv[2], bpv[3]);
                }
            }
        } else {
            // ---------------- high band: highpass = x - avg3 into tmp ----------------
            for (int p = tid; p < 17 * 17; p += 256) {
                const int pr = p / 17, pc = p % 17;
                const int br = pr * 4 - 1, bc = pc * 4 - 1;
                float v3a[4][4] = {};
                float cen[4][4];
                #pragma unroll
                for (int rr = 0; rr < 6; ++rr) {
                    // rows: xs idx pr*4+2 .. pr*4+7 (max 71, in range)
                    // cols: needed idx pc*4+2 .. pc*4+7 -> two aligned b128 at pc*4, pc*4+4
                    const float* row = &xs[(pr * 4 + 2 + rr) * 72 + pc * 4];
                    float v[8];
                    *reinterpret_cast<float4*>(&v[0]) = *reinterpret_cast<const float4*>(row);
                    *reinterpret_cast<float4*>(&v[4]) = *reinterpret_cast<const float4*>(row + 4);
                    float h3[4];
                    #pragma unroll
                    for (int j = 0; j < 4; ++j) h3[j] = v[j + 2] + v[j + 3] + v[j + 4];
                    if (rr >= 1 && rr <= 4) {
                        #pragma unroll
                        for (int j = 0; j < 4; ++j) cen[rr - 1][j] = v[j + 3];
                    }
                    #pragma unroll
                    for (int k = 0; k < 4; ++k) {
                        if (rr >= k && rr <= k + 2) {
                            #pragma unroll
                            for (int j = 0; j < 4; ++j) v3a[k][j] += h3[j];
                        }
                    }
                }
                float r3h[4], r3w[4];
                #pragma unroll
                for (int i = 0; i < 4; ++i) {
                    const int hh = th + br + i;
                    const int a3 = min(hh + 1, HH - 1) - max(hh - 1, 0) + 1;
                    r3h[i] = 1.0f / (float)a3;
                }
                #pragma unroll
                for (int j = 0; j < 4; ++j) {
                    const int ww = tw + bc + j;
                    const int a3 = min(ww + 1, WW - 1) - max(ww - 1, 0) + 1;
                    r3w[j] = 1.0f / (float)a3;
                }
                #pragma unroll
                for (int i = 0; i < 4; ++i) {
                    const int hh = th + br + i;
                    float hpv[4];
                    #pragma unroll
                    for (int j = 0; j < 4; ++j) {
                        const int ww = tw + bc + j;
                        float hp = 0.f;
                        if (hh >= 0 && hh < HH && ww >= 0 && ww < WW)
                            hp = cen[i][j] - v3a[i][j] * (r3h[i] * r3w[j]);
                        hpv[j] = hp;
                    }
                    *reinterpret_cast<float4*>(&tmp[(pr * 4 + i) * 68 + pc * 4]) =
                        make_float4(hpv[0], hpv[1], hpv[2], hpv[3]);
                }
            }
        }
        __syncthreads();

        // ---------------- 3x3 depthwise conv over tmp ----------------
        const float* __restrict__ wp = ((g == 1) ? w_mf : w_hf) + ci * 9;
        float wk[9];
        #pragma unroll
        for (int t = 0; t < 9; ++t) wk[t] = wp[t];
        #pragma unroll
        for (int i = 0; i < 4; ++i)
            #pragma unroll
            for (int j = 0; j < 4; ++j) acc[i][j] = 0.f;

        #pragma unroll
        for (int rr = 0; rr < 6; ++rr) {
            // tmp row coord = qr-1+rr -> idx qr+rr; cols coord qc-1.. -> idx qc..qc+5,
            // two aligned b128 at qc, qc+4 (elements 6,7 are unused padding lanes).
            const float* row = &tmp[(qr + rr) * 68 + qc];
            float v[8];
            *reinterpret_cast<float4*>(&v[0]) = *reinterpret_cast<const float4*>(row);
            *reinterpret_cast<float4*>(&v[4]) = *reinterpret_cast<const float4*>(row + 4);
            #pragma unroll
            for (int i = 0; i < 4; ++i) {
                const int ki = rr - i;
                if (ki >= 0 && ki < 3) {
                    #pragma unroll
                    for (int j = 0; j < 4; ++j)
                        acc[i][j] += v[j + 0] * wk[ki * 3 + 0]
                                   + v[j + 1] * wk[ki * 3 + 1]
                                   + v[j + 2] * wk[ki * 3 + 2];
                }
            }
        }
    }

    // ---------------- BN + SiLU + store (channel-shuffled) ----------------
    const float bninv  = gamma[c_out] * rsqrtf(var[c_out] + 1e-5f);
    const float bnbias = beta[c_out] - mean[c_out] * bninv;
    float* __restrict__ op = out + (((size_t)b * CC + c_out) * (size_t)HH + (th + qr)) * (size_t)WW + (tw + qc);
    #pragma unroll
    for (int i = 0; i < 4; ++i) {
        float4 o;
        const float z0 = acc[i][0] * bninv + bnbias;
        const float z1 = acc[i][1] * bninv + bnbias;
        const float z2 = acc[i][2] * bninv + bnbias;
        const float z3 = acc[i][3] * bninv + bnbias;
        o.x = silu_of(z0);
        o.y = silu_of(z1);
        o.z = silu_of(z2);
        o.w = silu_of(z3);
        *reinterpret_cast<float4*>(op + (size_t)i * WW) = o;
    }
}

extern "C" void kernel_launch(void* const* d_in, const int* in_sizes, int n_in,
                              void* d_out, int out_size, void* d_ws, size_t ws_size,
                              hipStream_t stream) {
    const float* x     = (const float*)d_in[0];
    const float* w_lo  = (const float*)d_in[1];
    const float* w_mf  = (const float*)d_in[2];
    const float* w_hf  = (const float*)d_in[3];
    const float* gam   = (const float*)d_in[4];
    const float* bet   = (const float*)d_in[5];
    const float* mea   = (const float*)d_in[6];
    const float* va    = (const float*)d_in[7];
    float* out = (float*)d_out;

    dim3 grid(16, CC, BB);
    dim3 block(256);
    hipLaunchKernelGGL(trifreq_kernel, grid, block, 0, stream,
                       x, w_lo, w_mf, w_hf, gam, bet, mea, va, out);
}